// Round 1
// baseline (2355.668 us; speedup 1.0000x reference)
//
#include <hip/hip_runtime.h>

// Decoder: h = relu(x @ W1 + b1); out = clamp(0.25*(h @ W2 + b2) + 0.5, 0, 1)
// B=262144, F=16, H=24, NOUT=784. All fp32. Memory-bound on the 822 MB output.

#define THREADS 256
#define ROWS_PER_BLOCK 256
#define F 16
#define H 24
#define NOUT 784

__launch_bounds__(THREADS, 3)
__global__ void decoder_kernel(const float* __restrict__ x,
                               const float* __restrict__ W1,
                               const float* __restrict__ b1,
                               const float* __restrict__ W2,
                               const float* __restrict__ b2,
                               float* __restrict__ out) {
    __shared__ float w1t[H][F];                 // W1 transposed: w1t[j][i]
    __shared__ float b1s[H];
    __shared__ float hbuf[ROWS_PER_BLOCK][H];   // 24 KB

    const int tid  = threadIdx.x;
    const int row0 = blockIdx.x * ROWS_PER_BLOCK;

    // ---- W2 columns + b2 into registers: thread owns cols [4*tid, 4*tid+3]
    const int  c0       = tid * 4;
    const bool has_cols = (c0 < NOUT);          // threads 196..255 idle in phase 2
    float4 w2r[H];
    float4 b2v = make_float4(0.f, 0.f, 0.f, 0.f);
    if (has_cols) {
        #pragma unroll
        for (int k = 0; k < H; ++k)
            w2r[k] = *reinterpret_cast<const float4*>(&W2[k * NOUT + c0]);
        b2v = *reinterpret_cast<const float4*>(&b2[c0]);
    }

    // ---- stage W1^T and b1 into LDS
    for (int idx = tid; idx < F * H; idx += THREADS) {
        const int i = idx / H, j = idx % H;     // W1 is [F][H] row-major
        w1t[j][i] = W1[idx];
    }
    if (tid < H) b1s[tid] = b1[tid];

    // ---- load this thread's x row (16 floats = 4 x float4)
    float4 xv[4];
    {
        const float* xr = x + (size_t)(row0 + tid) * F;
        #pragma unroll
        for (int q = 0; q < 4; ++q)
            xv[q] = *reinterpret_cast<const float4*>(&xr[q * 4]);
    }

    __syncthreads();

    // ---- phase 1: h = relu(x @ W1 + b1) for row (row0 + tid)
    {
        float hl[H];
        #pragma unroll
        for (int j = 0; j < H; ++j) {
            float acc = b1s[j];
            #pragma unroll
            for (int q = 0; q < 4; ++q) {
                const float4 wv = *reinterpret_cast<const float4*>(&w1t[j][q * 4]);
                acc = fmaf(xv[q].x, wv.x, acc);
                acc = fmaf(xv[q].y, wv.y, acc);
                acc = fmaf(xv[q].z, wv.z, acc);
                acc = fmaf(xv[q].w, wv.w, acc);
            }
            hl[j] = fmaxf(acc, 0.0f);
        }
        #pragma unroll
        for (int q = 0; q < 6; ++q) {
            float4 hv = make_float4(hl[q * 4 + 0], hl[q * 4 + 1],
                                    hl[q * 4 + 2], hl[q * 4 + 3]);
            *reinterpret_cast<float4*>(&hbuf[tid][q * 4]) = hv;
        }
    }

    __syncthreads();

    // ---- phase 2: out[r][c0..c0+3] = clamp(0.25*(h[r]@W2 + b2) + 0.5, 0, 1)
    if (has_cols) {
        float4* outp = reinterpret_cast<float4*>(out + (size_t)row0 * NOUT + c0);
        const int stride4 = NOUT / 4;           // 196 float4 per row
        for (int r = 0; r < ROWS_PER_BLOCK; ++r) {
            // broadcast-read h row (uniform address across the wave)
            float hl[H];
            #pragma unroll
            for (int q = 0; q < 6; ++q) {
                const float4 hv = *reinterpret_cast<const float4*>(&hbuf[r][q * 4]);
                hl[q * 4 + 0] = hv.x; hl[q * 4 + 1] = hv.y;
                hl[q * 4 + 2] = hv.z; hl[q * 4 + 3] = hv.w;
            }
            float4 acc = b2v;
            #pragma unroll
            for (int k = 0; k < H; ++k) {
                const float hk = hl[k];
                acc.x = fmaf(hk, w2r[k].x, acc.x);
                acc.y = fmaf(hk, w2r[k].y, acc.y);
                acc.z = fmaf(hk, w2r[k].z, acc.z);
                acc.w = fmaf(hk, w2r[k].w, acc.w);
            }
            float4 o;
            o.x = fminf(fmaxf(fmaf(acc.x, 0.25f, 0.5f), 0.f), 1.f);
            o.y = fminf(fmaxf(fmaf(acc.y, 0.25f, 0.5f), 0.f), 1.f);
            o.z = fminf(fmaxf(fmaf(acc.z, 0.25f, 0.5f), 0.f), 1.f);
            o.w = fminf(fmaxf(fmaf(acc.w, 0.25f, 0.5f), 0.f), 1.f);
            *outp = o;
            outp += stride4;
        }
    }
}

extern "C" void kernel_launch(void* const* d_in, const int* in_sizes, int n_in,
                              void* d_out, int out_size, void* d_ws, size_t ws_size,
                              hipStream_t stream) {
    const float* x  = (const float*)d_in[0];
    const float* W1 = (const float*)d_in[1];
    const float* b1 = (const float*)d_in[2];
    const float* W2 = (const float*)d_in[3];
    const float* b2 = (const float*)d_in[4];
    float* out = (float*)d_out;

    const int B = in_sizes[0] / F;              // 262144
    const int grid = B / ROWS_PER_BLOCK;        // 1024
    decoder_kernel<<<grid, THREADS, 0, stream>>>(x, W1, b1, W2, b2, out);
}

// Round 2
// 208.372 us; speedup vs baseline: 11.3051x; 11.3051x over previous
//
#include <hip/hip_runtime.h>

// Decoder: h = relu(x @ W1 + b1); out = clamp(0.25*(h @ W2 + b2) + 0.5, 0, 1)
// B=262144, F=16, H=24, NOUT=784. fp32. Memory-bound: 822 MB output write.
//
// Round-1 lesson: W2-columns-in-registers (24 x float4 = 96 VGPR) spilled to
// scratch when loaded inside a divergent branch far from use (VGPR=84, 4 GB
// scratch FETCH). Fix: load W2 regs unconditionally, right before the phase-2
// loop; launch_bounds(256,2) so the allocator has room (cap 256 VGPR).

#define THREADS 256
#define ROWS_PER_BLOCK 256
#define F 16
#define H 24
#define NOUT 784
#define NCHUNK (NOUT / 4)   // 196 float4 column-chunks per row

__launch_bounds__(THREADS, 2)
__global__ void decoder_kernel(const float* __restrict__ x,
                               const float* __restrict__ W1,
                               const float* __restrict__ b1,
                               const float* __restrict__ W2,
                               const float* __restrict__ b2,
                               float* __restrict__ out) {
    __shared__ float w1t[H][F];                 // W1 transposed: w1t[j][i]
    __shared__ float b1s[H];
    __shared__ float hbuf[ROWS_PER_BLOCK][H];   // 24 KB

    const int tid  = threadIdx.x;
    const int row0 = blockIdx.x * ROWS_PER_BLOCK;

    // ---- stage W1^T and b1 into LDS
    for (int idx = tid; idx < F * H; idx += THREADS) {
        const int i = idx / H, j = idx % H;     // W1 is [F][H] row-major
        w1t[j][i] = W1[idx];
    }
    if (tid < H) b1s[tid] = b1[tid];

    // ---- load this thread's x row (16 floats = 4 x float4)
    float4 xv[4];
    {
        const float* xr = x + (size_t)(row0 + tid) * F;
        #pragma unroll
        for (int q = 0; q < 4; ++q)
            xv[q] = *reinterpret_cast<const float4*>(&xr[q * 4]);
    }

    __syncthreads();

    // ---- phase 1: h = relu(x @ W1 + b1) for row (row0 + tid)
    #pragma unroll
    for (int q6 = 0; q6 < 6; ++q6) {
        float hv[4];
        #pragma unroll
        for (int jj = 0; jj < 4; ++jj) {
            const int j = q6 * 4 + jj;
            float acc = b1s[j];
            #pragma unroll
            for (int q = 0; q < 4; ++q) {
                const float4 wv = *reinterpret_cast<const float4*>(&w1t[j][q * 4]);
                acc = fmaf(xv[q].x, wv.x, acc);
                acc = fmaf(xv[q].y, wv.y, acc);
                acc = fmaf(xv[q].z, wv.z, acc);
                acc = fmaf(xv[q].w, wv.w, acc);
            }
            hv[jj] = fmaxf(acc, 0.0f);
        }
        *reinterpret_cast<float4*>(&hbuf[tid][q6 * 4]) =
            make_float4(hv[0], hv[1], hv[2], hv[3]);
    }

    __syncthreads();

    // ---- phase 2: thread owns output columns [c0, c0+3] for all 256 rows.
    // Load W2 columns + b2 into registers HERE (unconditional, adjacent to
    // use) so the allocator keeps them in VGPRs.
    const int  cc = (tid < NCHUNK) ? tid : (NCHUNK - 1);   // clamp, no branch
    const int  c0 = cc * 4;
    float4 w2r[H];
    #pragma unroll
    for (int k = 0; k < H; ++k)
        w2r[k] = *reinterpret_cast<const float4*>(&W2[k * NOUT + c0]);
    const float4 b2v = *reinterpret_cast<const float4*>(&b2[c0]);

    if (tid < NCHUNK) {
        float* outp = out + (size_t)row0 * NOUT + c0;
        for (int r = 0; r < ROWS_PER_BLOCK; ++r) {
            float4 acc = b2v;
            #pragma unroll
            for (int q = 0; q < 6; ++q) {
                // uniform address across the wave -> LDS broadcast, no conflict
                const float4 hv = *reinterpret_cast<const float4*>(&hbuf[r][q * 4]);
                const float h0 = hv.x, h1 = hv.y, h2 = hv.z, h3 = hv.w;
                acc.x = fmaf(h0, w2r[q * 4 + 0].x, acc.x);
                acc.y = fmaf(h0, w2r[q * 4 + 0].y, acc.y);
                acc.z = fmaf(h0, w2r[q * 4 + 0].z, acc.z);
                acc.w = fmaf(h0, w2r[q * 4 + 0].w, acc.w);
                acc.x = fmaf(h1, w2r[q * 4 + 1].x, acc.x);
                acc.y = fmaf(h1, w2r[q * 4 + 1].y, acc.y);
                acc.z = fmaf(h1, w2r[q * 4 + 1].z, acc.z);
                acc.w = fmaf(h1, w2r[q * 4 + 1].w, acc.w);
                acc.x = fmaf(h2, w2r[q * 4 + 2].x, acc.x);
                acc.y = fmaf(h2, w2r[q * 4 + 2].y, acc.y);
                acc.z = fmaf(h2, w2r[q * 4 + 2].z, acc.z);
                acc.w = fmaf(h2, w2r[q * 4 + 2].w, acc.w);
                acc.x = fmaf(h3, w2r[q * 4 + 3].x, acc.x);
                acc.y = fmaf(h3, w2r[q * 4 + 3].y, acc.y);
                acc.z = fmaf(h3, w2r[q * 4 + 3].z, acc.z);
                acc.w = fmaf(h3, w2r[q * 4 + 3].w, acc.w);
            }
            float4 o;
            o.x = fminf(fmaxf(fmaf(acc.x, 0.25f, 0.5f), 0.f), 1.f);
            o.y = fminf(fmaxf(fmaf(acc.y, 0.25f, 0.5f), 0.f), 1.f);
            o.z = fminf(fmaxf(fmaf(acc.z, 0.25f, 0.5f), 0.f), 1.f);
            o.w = fminf(fmaxf(fmaf(acc.w, 0.25f, 0.5f), 0.f), 1.f);
            *reinterpret_cast<float4*>(outp) = o;
            outp += NOUT;
        }
    }
}

extern "C" void kernel_launch(void* const* d_in, const int* in_sizes, int n_in,
                              void* d_out, int out_size, void* d_ws, size_t ws_size,
                              hipStream_t stream) {
    const float* x  = (const float*)d_in[0];
    const float* W1 = (const float*)d_in[1];
    const float* b1 = (const float*)d_in[2];
    const float* W2 = (const float*)d_in[3];
    const float* b2 = (const float*)d_in[4];
    float* out = (float*)d_out;

    const int B = in_sizes[0] / F;              // 262144
    const int grid = B / ROWS_PER_BLOCK;        // 1024
    decoder_kernel<<<grid, THREADS, 0, stream>>>(x, W1, b1, W2, b2, out);
}